// Round 2
// baseline (6072.501 us; speedup 1.0000x reference)
//
#include <hip/hip_runtime.h>

// Problem constants: B=2, H=256, W=448, fp32. Pipeline is run PER BATCH to
// keep the workspace footprint at 275 planes * H*W * 4B ~= 120 MiB.
#define HH 256
#define WW 448
#define HW (HH * WW)

// ---------------------------------------------------------------------------
// Generic 3x3 SAME conv (single batch), NCHW input, NCHW or NHWC output,
// optional ReLU, optional residual add (NCHW, Cout channels).
// Block = 256 threads = 16x16 spatial tile; each thread computes COB output
// channels for one pixel. Input channels staged in LDS in chunks of 8.
// ---------------------------------------------------------------------------
template <int COB>
__global__ __launch_bounds__(256) void conv3x3_k(
    const float* __restrict__ in, const float* __restrict__ wt,
    const float* __restrict__ bias, float* __restrict__ out,
    const float* __restrict__ residual,
    int Cin, int Cout, int relu, int nhwcOut)
{
    const int H = HH, W = WW;
    const int tx = threadIdx.x & 15;
    const int ty = threadIdx.x >> 4;
    const int x0 = blockIdx.x * 16;
    const int y0 = blockIdx.y * 16;
    const int coBase = blockIdx.z * COB;
    const int x = x0 + tx, y = y0 + ty;

    __shared__ float tile[8][18][18];

    float acc[COB];
#pragma unroll
    for (int j = 0; j < COB; ++j) acc[j] = bias[coBase + j];

    for (int ci0 = 0; ci0 < Cin; ci0 += 8) {
        const int cc = min(8, Cin - ci0);
        const int total = cc * 324;  // cc * 18 * 18
        for (int idx = threadIdx.x; idx < total; idx += 256) {
            int ci = idx / 324;
            int rem = idx - ci * 324;
            int ry = rem / 18;
            int rx = rem - ry * 18;
            int gy = y0 + ry - 1;
            int gx = x0 + rx - 1;
            float v = 0.f;
            if (gy >= 0 && gy < H && gx >= 0 && gx < W)
                v = in[((size_t)(ci0 + ci) * H + gy) * W + gx];
            tile[ci][ry][rx] = v;
        }
        __syncthreads();

        for (int ci = 0; ci < cc; ++ci) {
            const float* wp = wt + ((size_t)coBase * Cin + (ci0 + ci)) * 9;
            const size_t js = (size_t)Cin * 9;
#pragma unroll
            for (int k = 0; k < 9; ++k) {
                const int ky = k / 3;
                const int kx = k - ky * 3;
                const float v = tile[ci][ty + ky][tx + kx];
#pragma unroll
                for (int j = 0; j < COB; ++j)
                    acc[j] = fmaf(v, wp[(size_t)j * js + k], acc[j]);
            }
        }
        __syncthreads();
    }

    if (x < W && y < H) {
#pragma unroll
        for (int j = 0; j < COB; ++j) {
            float v = acc[j];
            if (relu) v = fmaxf(v, 0.f);
            if (residual)
                v += residual[((size_t)(coBase + j) * H + y) * W + x];
            size_t o = nhwcOut
                ? (((size_t)y * W + x) * Cout + coBase + j)
                : (((size_t)(coBase + j) * H + y) * W + x);
            out[o] = v;
        }
    }
}

// ---------------------------------------------------------------------------
// Bilinear warp, border padding, align_corners=True (single batch).
// f2 NHWC (H,W,32); flow NCHW (2,H,W); out NHWC (H,W,32).
// ---------------------------------------------------------------------------
__global__ __launch_bounds__(256) void warp_k(
    const float* __restrict__ f2, const float* __restrict__ flow,
    float* __restrict__ out)
{
    const int H = HH, W = WW, C = 32;
    int idx = blockIdx.x * 256 + threadIdx.x;
    if (idx >= H * W) return;
    int y = idx / W;
    int x = idx - y * W;

    float px = (float)x + flow[idx];
    float py = (float)y + flow[idx + (size_t)H * W];
    px = fminf(fmaxf(px, 0.f), (float)(W - 1));
    py = fminf(fmaxf(py, 0.f), (float)(H - 1));
    float fx0 = floorf(px), fy0 = floorf(py);
    int xi0 = (int)fx0, yi0 = (int)fy0;
    int xi1 = min(xi0 + 1, W - 1), yi1 = min(yi0 + 1, H - 1);
    float wx = px - fx0, wy = py - fy0;
    float w00 = (1.f - wx) * (1.f - wy);
    float w01 = wx * (1.f - wy);
    float w10 = (1.f - wx) * wy;
    float w11 = wx * wy;

    const float4* p00 = (const float4*)(f2 + ((size_t)yi0 * W + xi0) * C);
    const float4* p01 = (const float4*)(f2 + ((size_t)yi0 * W + xi1) * C);
    const float4* p10 = (const float4*)(f2 + ((size_t)yi1 * W + xi0) * C);
    const float4* p11 = (const float4*)(f2 + ((size_t)yi1 * W + xi1) * C);
    float4* po = (float4*)(out + ((size_t)y * W + x) * C);
#pragma unroll
    for (int j = 0; j < 8; ++j) {
        float4 a = p00[j], bq = p01[j], c = p10[j], d = p11[j];
        float4 r;
        r.x = a.x * w00 + bq.x * w01 + c.x * w10 + d.x * w11;
        r.y = a.y * w00 + bq.y * w01 + c.y * w10 + d.y * w11;
        r.z = a.z * w00 + bq.z * w01 + c.z * w10 + d.z * w11;
        r.w = a.w * w00 + bq.w * w01 + c.w * w10 + d.w * w11;
        po[j] = r;
    }
}

// ---------------------------------------------------------------------------
// Cost volume (single batch): integer offsets through bilinear_border reduce
// to border-clamped integer shifts (wx=wy=0 exactly). One thread per
// (pixel, dy); 9 dx offsets each. f1/f2w NHWC; writes NCHW ch [0,81) of h.
// ---------------------------------------------------------------------------
__global__ __launch_bounds__(256) void cost_k(
    const float* __restrict__ f1, const float* __restrict__ f2w,
    float* __restrict__ hbuf)
{
    const int H = HH, W = WW, C = 32;
    const int tx = threadIdx.x & 15;
    const int ty = threadIdx.x >> 4;
    const int x = blockIdx.x * 16 + tx;
    const int y = blockIdx.y * 16 + ty;
    const int dyi = blockIdx.z;

    float4 f[8];
    const float4* fp = (const float4*)(f1 + ((size_t)y * W + x) * C);
#pragma unroll
    for (int j = 0; j < 8; ++j) f[j] = fp[j];

    const int yy = min(max(y + dyi - 4, 0), H - 1);
    for (int dxi = 0; dxi < 9; ++dxi) {
        const int xx = min(max(x + dxi - 4, 0), W - 1);
        const float4* gp = (const float4*)(f2w + ((size_t)yy * W + xx) * C);
        float s = 0.f;
#pragma unroll
        for (int j = 0; j < 8; ++j) {
            float4 g = gp[j];
            s = fmaf(f[j].x, g.x, s);
            s = fmaf(f[j].y, g.y, s);
            s = fmaf(f[j].z, g.z, s);
            s = fmaf(f[j].w, g.w, s);
        }
        hbuf[((size_t)(dyi * 9 + dxi) * H + y) * W + x] = s;
    }
}

// Copy initial_flow (2,H,W) into channels 81..82 of the 83-channel h buffer.
__global__ __launch_bounds__(256) void copyflow_k(
    const float* __restrict__ flow, float* __restrict__ hbuf)
{
    int idx = blockIdx.x * 256 + threadIdx.x;
    if (idx >= 2 * HW) return;
    hbuf[(size_t)81 * HW + idx] = flow[idx];
}

extern "C" void kernel_launch(void* const* d_in, const int* in_sizes, int n_in,
                              void* d_out, int out_size, void* d_ws, size_t ws_size,
                              hipStream_t stream)
{
    (void)in_sizes; (void)n_in; (void)out_size; (void)ws_size;
    const float* feat1 = (const float*)d_in[0];
    const float* feat2 = (const float*)d_in[1];
    const float* iflow = (const float*)d_in[2];
    const float* fW1 = (const float*)d_in[3];  const float* fb1 = (const float*)d_in[4];
    const float* fW2 = (const float*)d_in[5];  const float* fb2 = (const float*)d_in[6];
    const float* fW3 = (const float*)d_in[7];  const float* fb3 = (const float*)d_in[8];
    const float* rW1 = (const float*)d_in[9];  const float* rb1 = (const float*)d_in[10];
    const float* rW2 = (const float*)d_in[11]; const float* rb2 = (const float*)d_in[12];
    const float* rW3 = (const float*)d_in[13]; const float* rb3 = (const float*)d_in[14];
    const float* rW4 = (const float*)d_in[15]; const float* rb4 = (const float*)d_in[16];
    float* out = (float*)d_out;

    // Per-batch arena (floats, HW planes):
    //   [A 64][B 64][S1 32][S2 32][H 83] = 275 planes ~= 120 MiB
    float* ws = (float*)d_ws;
    float* A  = ws;
    float* Bf = A + (size_t)64 * HW;
    float* S1 = Bf + (size_t)64 * HW;
    float* S2 = S1 + (size_t)32 * HW;
    float* Hb = S2 + (size_t)32 * HW;
    float* R1 = A;    // 128 planes = A+B       (dead after extractor)
    float* R2 = S1;   // 128 planes = S1+S2+H[0:64]  (dead after rconv1)
    float* R3 = A;    // 64 planes               (R1 dead after rconv2)

    const dim3 blk(256);
    const int GX = WW / 16, GY = HH / 16;  // 28, 16

    for (int b = 0; b < 2; ++b) {
        const float* f1in = feat1 + (size_t)b * 3 * HW;
        const float* f2in = feat2 + (size_t)b * 3 * HW;
        const float* flw  = iflow + (size_t)b * 2 * HW;
        float* outb = out + (size_t)b * 2 * HW;

        // Extractor on feat2 first (we only need its warped result S2).
        conv3x3_k<8><<<dim3(GX, GY, 8), blk, 0, stream>>>(f2in, fW1, fb1, A,  nullptr, 3,  64, 1, 0);
        conv3x3_k<8><<<dim3(GX, GY, 8), blk, 0, stream>>>(A,    fW2, fb2, Bf, nullptr, 64, 64, 1, 0);
        conv3x3_k<8><<<dim3(GX, GY, 4), blk, 0, stream>>>(Bf,   fW3, fb3, S1, nullptr, 64, 32, 1, 1);
        warp_k<<<dim3((HW + 255) / 256), blk, 0, stream>>>(S1, flw, S2);

        // Extractor on feat1 -> S1 (overwrites F2, which is dead).
        conv3x3_k<8><<<dim3(GX, GY, 8), blk, 0, stream>>>(f1in, fW1, fb1, A,  nullptr, 3,  64, 1, 0);
        conv3x3_k<8><<<dim3(GX, GY, 8), blk, 0, stream>>>(A,    fW2, fb2, Bf, nullptr, 64, 64, 1, 0);
        conv3x3_k<8><<<dim3(GX, GY, 4), blk, 0, stream>>>(Bf,   fW3, fb3, S1, nullptr, 64, 32, 1, 1);

        // Cost volume + flow channels.
        cost_k<<<dim3(GX, GY, 9), blk, 0, stream>>>(S1, S2, Hb);
        copyflow_k<<<dim3((2 * HW + 255) / 256), blk, 0, stream>>>(flw, Hb);

        // Refinement head.
        conv3x3_k<8><<<dim3(GX, GY, 16), blk, 0, stream>>>(Hb, rW1, rb1, R1, nullptr, 83,  128, 1, 0);
        conv3x3_k<8><<<dim3(GX, GY, 16), blk, 0, stream>>>(R1, rW2, rb2, R2, nullptr, 128, 128, 1, 0);
        conv3x3_k<8><<<dim3(GX, GY, 8),  blk, 0, stream>>>(R2, rW3, rb3, R3, nullptr, 128, 64,  1, 0);
        conv3x3_k<2><<<dim3(GX, GY, 1),  blk, 0, stream>>>(R3, rW4, rb4, outb, flw,   64,  2,   0, 0);
    }
}

// Round 3
// 817.522 us; speedup vs baseline: 7.4279x; 7.4279x over previous
//
#include <hip/hip_runtime.h>

// B=2, H=256, W=448. Pipeline per batch. bf16 MFMA for the 5 big convs.
#define HH 256
#define WW 448
#define HW (HH * WW)

typedef short bf16x8 __attribute__((ext_vector_type(8)));
typedef float f32x4 __attribute__((ext_vector_type(4)));
typedef unsigned int uint32;

__device__ __forceinline__ float bf2f(unsigned short u) {
    return __uint_as_float(((uint32)u) << 16);
}
__device__ __forceinline__ unsigned short f2bf(float f) {
    uint32 u = __float_as_uint(f);
    u += 0x7fffu + ((u >> 16) & 1u);  // RNE
    return (unsigned short)(u >> 16);
}

// ---------------------------------------------------------------------------
// Weight repack: fp32 OIHW (Cout,CinReal,3,3) -> bf16 [tap][kc][n][32]
// (B-fragment order: 32 consecutive k per n). Zero-fills cin >= CinReal.
// ---------------------------------------------------------------------------
__global__ __launch_bounds__(256) void pack_w_k(
    const float* __restrict__ w, unsigned short* __restrict__ wp,
    int CinReal, int CinPad, int Cout)
{
    int total = 9 * CinPad * Cout;
    int i = blockIdx.x * 256 + threadIdx.x;
    if (i >= total) return;
    int ci = i & 31;
    int rest = i >> 5;
    int n = rest % Cout;
    int rest2 = rest / Cout;
    int KC = CinPad / 32;
    int kc = rest2 % KC;
    int tap = rest2 / KC;
    int cin = kc * 32 + ci;
    float v = (cin < CinReal) ? w[((size_t)n * CinReal + cin) * 9 + tap] : 0.f;
    wp[i] = f2bf(v);
}

// ---------------------------------------------------------------------------
// MFMA implicit-GEMM 3x3 SAME conv. NHWC bf16 in/out, fp32 bias, optional
// ReLU. Block 256 = 4 waves; tile = 8 rows x 16 cols = 128 px; full Cin halo
// patch (10x18xCin, stride Cin+8 -> <=2-way LDS conflicts) staged once.
// mfma_f32_16x16x32_bf16: A[m=lane&15][k=quad*8+j], B[k=quad*8+j][n=lane&15],
// D row m=quad*4+reg, col n=lane&15 (m = column within the 16-px row tile).
// ---------------------------------------------------------------------------
template <int CIN, int COUT, int RELU>
__global__ __launch_bounds__(256) void convmfma_k(
    const unsigned short* __restrict__ in,
    const unsigned short* __restrict__ wp,
    const float* __restrict__ bias,
    unsigned short* __restrict__ out)
{
    constexpr int KC = CIN / 32;
    constexpr int CS = CIN + 8;                 // bf16 elems per pixel in LDS
    constexpr int MG = (COUT == 32) ? 4 : 2;    // m-groups of waves
    constexpr int WM = 8 / MG;                  // m-tiles per wave
    constexpr int NG = 4 / MG;                  // n-groups of waves
    constexpr int WN = (COUT / 16) / NG;        // n-tiles per wave
    constexpr int CH8 = CIN / 8;

    __shared__ __align__(16) unsigned short lds[180 * CS];

    const int tid = threadIdx.x;
    const int x0 = blockIdx.x * 16;
    const int y0 = blockIdx.y * 8;

    // Stage halo patch (zero pad outside image).
    for (int i = tid; i < 180 * CH8; i += 256) {
        int p = i / CH8, c8 = i - p * CH8;
        int ry = p / 18, rx = p - ry * 18;
        int gy = y0 + ry - 1, gx = x0 + rx - 1;
        float4 v = make_float4(0.f, 0.f, 0.f, 0.f);
        if (gy >= 0 && gy < HH && gx >= 0 && gx < WW)
            v = *(const float4*)(in + ((size_t)gy * WW + gx) * CIN + c8 * 8);
        *(float4*)(lds + p * CS + c8 * 8) = v;
    }
    __syncthreads();

    const int wv = tid >> 6;
    const int lane = tid & 63;
    const int m = lane & 15;
    const int quad = lane >> 4;
    const int mbase = (wv % MG) * WM;       // tile-row base
    const int nbase = (wv / MG) * WN * 16;  // cout base

    f32x4 acc[WM][WN];
#pragma unroll
    for (int t = 0; t < WM; ++t)
#pragma unroll
        for (int u = 0; u < WN; ++u)
            acc[t][u] = (f32x4){0.f, 0.f, 0.f, 0.f};

    for (int tap = 0; tap < 9; ++tap) {
        const int ky = tap / 3;
        const int kx = tap - 3 * ky;
#pragma unroll
        for (int kc = 0; kc < KC; ++kc) {
            bf16x8 a[WM], b[WN];
#pragma unroll
            for (int t = 0; t < WM; ++t)
                a[t] = *(const bf16x8*)(lds +
                        ((mbase + t + ky) * 18 + (m + kx)) * CS + kc * 32 + quad * 8);
#pragma unroll
            for (int u = 0; u < WN; ++u)
                b[u] = *(const bf16x8*)(wp +
                        ((size_t)(tap * KC + kc) * COUT + nbase + u * 16 + m) * 32 + quad * 8);
#pragma unroll
            for (int t = 0; t < WM; ++t)
#pragma unroll
                for (int u = 0; u < WN; ++u)
                    acc[t][u] = __builtin_amdgcn_mfma_f32_16x16x32_bf16(
                        a[t], b[u], acc[t][u], 0, 0, 0);
        }
    }

#pragma unroll
    for (int u = 0; u < WN; ++u) {
        const int n = nbase + u * 16 + m;
        const float bs = bias[n];
#pragma unroll
        for (int t = 0; t < WM; ++t) {
            const int y = y0 + mbase + t;
#pragma unroll
            for (int r = 0; r < 4; ++r) {
                const int x = x0 + quad * 4 + r;
                float v = acc[t][u][r] + bs;
                if (RELU) v = fmaxf(v, 0.f);
                out[((size_t)y * WW + x) * COUT + n] = f2bf(v);
            }
        }
    }
}

// ---------------------------------------------------------------------------
// fconv1: fp32 NCHW (3,H,W) -> bf16 NHWC 64ch, ReLU. Block 256 = 32 px x 8
// channel-groups (8 couts each) so stores are coalesced float4s.
// ---------------------------------------------------------------------------
__global__ __launch_bounds__(256) void fconv1_k(
    const float* __restrict__ in, const float* __restrict__ w,
    const float* __restrict__ bias, unsigned short* __restrict__ out)
{
    __shared__ float wl[1728];          // 64*3*9
    __shared__ float patch[3][4][18];   // 2-row tile + halo
    const int tid = threadIdx.x;
    const int x0 = blockIdx.x * 16, y0 = blockIdx.y * 2;
    for (int i = tid; i < 1728; i += 256) wl[i] = w[i];
    for (int i = tid; i < 216; i += 256) {
        int ci = i / 72;
        int r = (i - ci * 72) / 18;
        int c = i - ci * 72 - r * 18;
        int gy = y0 + r - 1, gx = x0 + c - 1;
        patch[ci][r][c] = (gy >= 0 && gy < HH && gx >= 0 && gx < WW)
                              ? in[(size_t)ci * HW + gy * WW + gx] : 0.f;
    }
    __syncthreads();
    const int g = tid & 7;
    const int p = tid >> 3;
    const int py = p >> 4, px = p & 15;
    float acc[8];
#pragma unroll
    for (int j = 0; j < 8; ++j) acc[j] = bias[g * 8 + j];
#pragma unroll
    for (int ci = 0; ci < 3; ++ci)
#pragma unroll
        for (int k = 0; k < 9; ++k) {
            const int ky = k / 3, kx = k - 3 * ky;
            const float v = patch[ci][py + ky][px + kx];
#pragma unroll
            for (int j = 0; j < 8; ++j)
                acc[j] = fmaf(v, wl[(g * 8 + j) * 27 + ci * 9 + k], acc[j]);
        }
    unsigned short ov[8];
#pragma unroll
    for (int j = 0; j < 8; ++j) ov[j] = f2bf(fmaxf(acc[j], 0.f));
    const int y = y0 + py, x = x0 + px;
    *(float4*)(out + ((size_t)y * WW + x) * 64 + g * 8) = *(const float4*)ov;
}

// ---------------------------------------------------------------------------
// Bilinear warp, border padding, align_corners=True. NHWC bf16 32ch.
// ---------------------------------------------------------------------------
__global__ __launch_bounds__(256) void warp_k(
    const unsigned short* __restrict__ f2, const float* __restrict__ flow,
    unsigned short* __restrict__ outp)
{
    int idx = blockIdx.x * 256 + threadIdx.x;
    if (idx >= HW) return;
    int y = idx / WW, x = idx - y * WW;
    float px_ = (float)x + flow[idx];
    float py_ = (float)y + flow[idx + HW];
    px_ = fminf(fmaxf(px_, 0.f), (float)(WW - 1));
    py_ = fminf(fmaxf(py_, 0.f), (float)(HH - 1));
    float fx0 = floorf(px_), fy0 = floorf(py_);
    int xi0 = (int)fx0, yi0 = (int)fy0;
    int xi1 = min(xi0 + 1, WW - 1), yi1 = min(yi0 + 1, HH - 1);
    float wx = px_ - fx0, wy = py_ - fy0;
    float w00 = (1.f - wx) * (1.f - wy), w01 = wx * (1.f - wy);
    float w10 = (1.f - wx) * wy, w11 = wx * wy;

    const uint32* a = (const uint32*)(f2 + ((size_t)yi0 * WW + xi0) * 32);
    const uint32* b = (const uint32*)(f2 + ((size_t)yi0 * WW + xi1) * 32);
    const uint32* c = (const uint32*)(f2 + ((size_t)yi1 * WW + xi0) * 32);
    const uint32* d = (const uint32*)(f2 + ((size_t)yi1 * WW + xi1) * 32);
    uint32 ov[16];
#pragma unroll
    for (int i = 0; i < 16; ++i) {
        uint32 wa = a[i], wb = b[i], wc = c[i], wd = d[i];
        float lo = __uint_as_float(wa << 16) * w00 + __uint_as_float(wb << 16) * w01 +
                   __uint_as_float(wc << 16) * w10 + __uint_as_float(wd << 16) * w11;
        float hi = __uint_as_float(wa & 0xffff0000u) * w00 + __uint_as_float(wb & 0xffff0000u) * w01 +
                   __uint_as_float(wc & 0xffff0000u) * w10 + __uint_as_float(wd & 0xffff0000u) * w11;
        ov[i] = ((uint32)f2bf(hi) << 16) | f2bf(lo);
    }
    uint32* o = (uint32*)(outp + (size_t)idx * 32);
#pragma unroll
    for (int i = 0; i < 16; ++i) o[i] = ov[i];
}

// ---------------------------------------------------------------------------
// Cost volume (+flow+zero-pad channels): integer offsets == clamped shifts.
// One thread per (pixel, dy). f1/f2w NHWC bf16 32ch; hb NHWC bf16 96ch.
// ---------------------------------------------------------------------------
__global__ __launch_bounds__(256) void cost_k(
    const unsigned short* __restrict__ f1, const unsigned short* __restrict__ f2w,
    const float* __restrict__ flow, unsigned short* __restrict__ hb)
{
    int gid = blockIdx.x * 256 + threadIdx.x;
    if (gid >= HW * 9) return;
    int dyi = gid / HW;
    int px = gid - dyi * HW;
    int y = px / WW, x = px - y * WW;

    float f[32];
    const uint32* fp = (const uint32*)(f1 + (size_t)px * 32);
#pragma unroll
    for (int i = 0; i < 16; ++i) {
        uint32 w = fp[i];
        f[2 * i] = __uint_as_float(w << 16);
        f[2 * i + 1] = __uint_as_float(w & 0xffff0000u);
    }
    int yy = min(max(y + dyi - 4, 0), HH - 1);
    unsigned short* ho = hb + (size_t)px * 96 + dyi * 9;
    for (int dxi = 0; dxi < 9; ++dxi) {
        int xx = min(max(x + dxi - 4, 0), WW - 1);
        const uint32* gp = (const uint32*)(f2w + ((size_t)yy * WW + xx) * 32);
        float s = 0.f;
#pragma unroll
        for (int i = 0; i < 16; ++i) {
            uint32 w = gp[i];
            s = fmaf(f[2 * i], __uint_as_float(w << 16), s);
            s = fmaf(f[2 * i + 1], __uint_as_float(w & 0xffff0000u), s);
        }
        ho[dxi] = f2bf(s);
    }
    if (dyi == 0) {
        unsigned short* hq = hb + (size_t)px * 96;
        hq[81] = f2bf(flow[px]);
        hq[82] = f2bf(flow[px + HW]);
#pragma unroll
        for (int c = 83; c < 96; ++c) hq[c] = 0;
    }
}

// ---------------------------------------------------------------------------
// rconv4: 64 -> 2, + initial_flow residual, fp32 NCHW output, no ReLU.
// ---------------------------------------------------------------------------
__global__ __launch_bounds__(256) void rconv4_k(
    const unsigned short* __restrict__ in, const float* __restrict__ w,
    const float* __restrict__ bias, const float* __restrict__ flow,
    float* __restrict__ out)
{
    __shared__ float wl[1152];  // 2*64*9
    for (int i = threadIdx.x; i < 1152; i += 256) wl[i] = w[i];
    __syncthreads();
    int px = blockIdx.x * 256 + threadIdx.x;
    if (px >= HW) return;
    int y = px / WW, x = px - y * WW;
    float a0 = bias[0], a1 = bias[1];
    for (int ky = 0; ky < 3; ++ky) {
        int gy = y + ky - 1;
        if (gy < 0 || gy >= HH) continue;
        for (int kx = 0; kx < 3; ++kx) {
            int gx = x + kx - 1;
            if (gx < 0 || gx >= WW) continue;
            const uint32* p = (const uint32*)(in + ((size_t)gy * WW + gx) * 64);
            int tap = ky * 3 + kx;
#pragma unroll
            for (int i = 0; i < 32; ++i) {
                uint32 wv = p[i];
                float lo = __uint_as_float(wv << 16);
                float hi = __uint_as_float(wv & 0xffff0000u);
                a0 = fmaf(lo, wl[(2 * i) * 9 + tap], a0);
                a0 = fmaf(hi, wl[(2 * i + 1) * 9 + tap], a0);
                a1 = fmaf(lo, wl[576 + (2 * i) * 9 + tap], a1);
                a1 = fmaf(hi, wl[576 + (2 * i + 1) * 9 + tap], a1);
            }
        }
    }
    out[px] = flow[px] + a0;
    out[px + HW] = flow[px + HW] + a1;
}

extern "C" void kernel_launch(void* const* d_in, const int* in_sizes, int n_in,
                              void* d_out, int out_size, void* d_ws, size_t ws_size,
                              hipStream_t stream)
{
    (void)in_sizes; (void)n_in; (void)out_size; (void)ws_size;
    const float* feat1 = (const float*)d_in[0];
    const float* feat2 = (const float*)d_in[1];
    const float* iflow = (const float*)d_in[2];
    const float* fW1 = (const float*)d_in[3];  const float* fb1 = (const float*)d_in[4];
    const float* fW2 = (const float*)d_in[5];  const float* fb2 = (const float*)d_in[6];
    const float* fW3 = (const float*)d_in[7];  const float* fb3 = (const float*)d_in[8];
    const float* rW1 = (const float*)d_in[9];  const float* rb1 = (const float*)d_in[10];
    const float* rW2 = (const float*)d_in[11]; const float* rb2 = (const float*)d_in[12];
    const float* rW3 = (const float*)d_in[13]; const float* rb3 = (const float*)d_in[14];
    const float* rW4 = (const float*)d_in[15]; const float* rb4 = (const float*)d_in[16];
    float* out = (float*)d_out;

    // Arena (bf16 elems). Per-batch buffers, reused across the 2 batches.
    // [X0 64][X1 64][F1 32][F2 32][F2W 32][Hb 96] = 320*HW elems (~73.4 MB)
    // R1 <- X0..X1 (128), R2 <- F2W..Hb (32+96=128), R3 <- F1..F2 (64).
    unsigned short* ws0 = (unsigned short*)d_ws;
    const size_t P = (size_t)HW;
    unsigned short* X0  = ws0;
    unsigned short* X1  = X0 + 64 * P;
    unsigned short* F1  = X1 + 64 * P;
    unsigned short* F2  = F1 + 32 * P;
    unsigned short* F2W = F2 + 32 * P;
    unsigned short* Hb  = F2W + 32 * P;
    unsigned short* R1  = X0;
    unsigned short* R2  = F2W;
    unsigned short* R3  = F1;
    unsigned short* wp2  = Hb + 96 * P;            // fconv2: 9*64*64
    unsigned short* wp3  = wp2 + 9 * 64 * 64;      // fconv3: 9*64*32
    unsigned short* wpr1 = wp3 + 9 * 64 * 32;      // rconv1: 9*96*128
    unsigned short* wpr2 = wpr1 + 9 * 96 * 128;    // rconv2: 9*128*128
    unsigned short* wpr3 = wpr2 + 9 * 128 * 128;   // rconv3: 9*128*64

    const dim3 blk(256);
    // Pack all conv weights (cheap, idempotent).
    pack_w_k<<<dim3((9 * 64 * 64 + 255) / 256), blk, 0, stream>>>(fW2, wp2, 64, 64, 64);
    pack_w_k<<<dim3((9 * 64 * 32 + 255) / 256), blk, 0, stream>>>(fW3, wp3, 64, 64, 32);
    pack_w_k<<<dim3((9 * 96 * 128 + 255) / 256), blk, 0, stream>>>(rW1, wpr1, 83, 96, 128);
    pack_w_k<<<dim3((9 * 128 * 128 + 255) / 256), blk, 0, stream>>>(rW2, wpr2, 128, 128, 128);
    pack_w_k<<<dim3((9 * 128 * 64 + 255) / 256), blk, 0, stream>>>(rW3, wpr3, 128, 128, 64);

    const dim3 gConv(WW / 16, HH / 8);   // 28 x 32
    const dim3 gF1(WW / 16, HH / 2);     // 28 x 128
    const int gPix = (HW + 255) / 256;

    for (int b = 0; b < 2; ++b) {
        const float* f1in = feat1 + (size_t)b * 3 * HW;
        const float* f2in = feat2 + (size_t)b * 3 * HW;
        const float* flw  = iflow + (size_t)b * 2 * HW;
        float* outb = out + (size_t)b * 2 * HW;

        // feat2 branch -> warped features
        fconv1_k<<<gF1, blk, 0, stream>>>(f2in, fW1, fb1, X0);
        convmfma_k<64, 64, 1><<<gConv, blk, 0, stream>>>(X0, wp2, fb2, X1);
        convmfma_k<64, 32, 1><<<gConv, blk, 0, stream>>>(X1, wp3, fb3, F2);
        warp_k<<<dim3(gPix), blk, 0, stream>>>(F2, flw, F2W);

        // feat1 branch
        fconv1_k<<<gF1, blk, 0, stream>>>(f1in, fW1, fb1, X0);
        convmfma_k<64, 64, 1><<<gConv, blk, 0, stream>>>(X0, wp2, fb2, X1);
        convmfma_k<64, 32, 1><<<gConv, blk, 0, stream>>>(X1, wp3, fb3, F1);

        // Cost volume (+ flow channels + zero pad) -> Hb (96ch NHWC)
        cost_k<<<dim3((HW * 9 + 255) / 256), blk, 0, stream>>>(F1, F2W, flw, Hb);

        // Refinement head
        convmfma_k<96, 128, 1><<<gConv, blk, 0, stream>>>(Hb, wpr1, rb1, R1);
        convmfma_k<128, 128, 1><<<gConv, blk, 0, stream>>>(R1, wpr2, rb2, R2);
        convmfma_k<128, 64, 1><<<gConv, blk, 0, stream>>>(R2, wpr3, rb3, R3);
        rconv4_k<<<dim3(gPix), blk, 0, stream>>>(R3, rW4, rb4, flw, outb);
    }
}

// Round 4
// 656.514 us; speedup vs baseline: 9.2496x; 1.2452x over previous
//
#include <hip/hip_runtime.h>

// B=2, H=256, W=448. Pipeline per batch. bf16 MFMA for the 5 big convs.
#define HH 256
#define WW 448
#define HW (HH * WW)

typedef short bf16x8 __attribute__((ext_vector_type(8)));
typedef float f32x4 __attribute__((ext_vector_type(4)));
typedef unsigned int uint32;

__device__ __forceinline__ float bf2f(unsigned short u) {
    return __uint_as_float(((uint32)u) << 16);
}
__device__ __forceinline__ unsigned short f2bf(float f) {
    uint32 u = __float_as_uint(f);
    u += 0x7fffu + ((u >> 16) & 1u);  // RNE
    return (unsigned short)(u >> 16);
}

// ---------------------------------------------------------------------------
// Weight repack: fp32 OIHW (Cout,CinReal,3,3) -> bf16 [tap][kc][n][32]
// (B-fragment order: 32 consecutive k per n). Zero-fills cin >= CinReal.
// ---------------------------------------------------------------------------
__global__ __launch_bounds__(256) void pack_w_k(
    const float* __restrict__ w, unsigned short* __restrict__ wp,
    int CinReal, int CinPad, int Cout)
{
    int total = 9 * CinPad * Cout;
    int i = blockIdx.x * 256 + threadIdx.x;
    if (i >= total) return;
    int ci = i & 31;
    int rest = i >> 5;
    int n = rest % Cout;
    int rest2 = rest / Cout;
    int KC = CinPad / 32;
    int kc = rest2 % KC;
    int tap = rest2 / KC;
    int cin = kc * 32 + ci;
    float v = (cin < CinReal) ? w[((size_t)n * CinReal + cin) * 9 + tap] : 0.f;
    wp[i] = f2bf(v);
}

// ---------------------------------------------------------------------------
// MFMA implicit-GEMM 3x3 SAME conv. NHWC bf16 in/out, fp32 bias, optional
// ReLU. Block 256 = 4 waves; tile = 8 rows x 16 cols = 128 px; full Cin halo
// patch (10x18xCin, stride Cin+8) staged once.
// mfma_f32_16x16x32_bf16: A[m=lane&15][k=quad*8+j], B[k=quad*8+j][n=lane&15],
// D row m=quad*4+reg, col n=lane&15 (m = column within the 16-px row tile).
// ---------------------------------------------------------------------------
template <int CIN, int COUT, int RELU>
__global__ __launch_bounds__(256) void convmfma_k(
    const unsigned short* __restrict__ in,
    const unsigned short* __restrict__ wp,
    const float* __restrict__ bias,
    unsigned short* __restrict__ out)
{
    constexpr int KC = CIN / 32;
    constexpr int CS = CIN + 8;                 // bf16 elems per pixel in LDS
    constexpr int MG = (COUT == 32) ? 4 : 2;    // m-groups of waves
    constexpr int WM = 8 / MG;                  // m-tiles per wave
    constexpr int NG = 4 / MG;                  // n-groups of waves
    constexpr int WN = (COUT / 16) / NG;        // n-tiles per wave
    constexpr int CH8 = CIN / 8;

    __shared__ __align__(16) unsigned short lds[180 * CS];

    const int tid = threadIdx.x;
    const int x0 = blockIdx.x * 16;
    const int y0 = blockIdx.y * 8;

    // Stage halo patch (zero pad outside image).
    for (int i = tid; i < 180 * CH8; i += 256) {
        int p = i / CH8, c8 = i - p * CH8;
        int ry = p / 18, rx = p - ry * 18;
        int gy = y0 + ry - 1, gx = x0 + rx - 1;
        float4 v = make_float4(0.f, 0.f, 0.f, 0.f);
        if (gy >= 0 && gy < HH && gx >= 0 && gx < WW)
            v = *(const float4*)(in + ((size_t)gy * WW + gx) * CIN + c8 * 8);
        *(float4*)(lds + p * CS + c8 * 8) = v;
    }
    __syncthreads();

    const int wv = tid >> 6;
    const int lane = tid & 63;
    const int m = lane & 15;
    const int quad = lane >> 4;
    const int mbase = (wv % MG) * WM;       // tile-row base
    const int nbase = (wv / MG) * WN * 16;  // cout base

    f32x4 acc[WM][WN];
#pragma unroll
    for (int t = 0; t < WM; ++t)
#pragma unroll
        for (int u = 0; u < WN; ++u)
            acc[t][u] = (f32x4){0.f, 0.f, 0.f, 0.f};

    for (int tap = 0; tap < 9; ++tap) {
        const int ky = tap / 3;
        const int kx = tap - 3 * ky;
#pragma unroll
        for (int kc = 0; kc < KC; ++kc) {
            bf16x8 a[WM], b[WN];
#pragma unroll
            for (int t = 0; t < WM; ++t)
                a[t] = *(const bf16x8*)(lds +
                        ((mbase + t + ky) * 18 + (m + kx)) * CS + kc * 32 + quad * 8);
#pragma unroll
            for (int u = 0; u < WN; ++u)
                b[u] = *(const bf16x8*)(wp +
                        ((size_t)(tap * KC + kc) * COUT + nbase + u * 16 + m) * 32 + quad * 8);
#pragma unroll
            for (int t = 0; t < WM; ++t)
#pragma unroll
                for (int u = 0; u < WN; ++u)
                    acc[t][u] = __builtin_amdgcn_mfma_f32_16x16x32_bf16(
                        a[t], b[u], acc[t][u], 0, 0, 0);
        }
    }

#pragma unroll
    for (int u = 0; u < WN; ++u) {
        const int n = nbase + u * 16 + m;
        const float bs = bias[n];
#pragma unroll
        for (int t = 0; t < WM; ++t) {
            const int y = y0 + mbase + t;
#pragma unroll
            for (int r = 0; r < 4; ++r) {
                const int x = x0 + quad * 4 + r;
                float v = acc[t][u][r] + bs;
                if (RELU) v = fmaxf(v, 0.f);
                out[((size_t)y * WW + x) * COUT + n] = f2bf(v);
            }
        }
    }
}

// ---------------------------------------------------------------------------
// fconv1: fp32 NCHW (3,H,W) -> bf16 NHWC 64ch, ReLU. Block 256 = 32 px x 8
// channel-groups (8 couts each) so stores are coalesced float4s.
// ---------------------------------------------------------------------------
__global__ __launch_bounds__(256) void fconv1_k(
    const float* __restrict__ in, const float* __restrict__ w,
    const float* __restrict__ bias, unsigned short* __restrict__ out)
{
    __shared__ float wl[1728];          // 64*3*9
    __shared__ float patch[3][4][18];   // 2-row tile + halo
    const int tid = threadIdx.x;
    const int x0 = blockIdx.x * 16, y0 = blockIdx.y * 2;
    for (int i = tid; i < 1728; i += 256) wl[i] = w[i];
    for (int i = tid; i < 216; i += 256) {
        int ci = i / 72;
        int r = (i - ci * 72) / 18;
        int c = i - ci * 72 - r * 18;
        int gy = y0 + r - 1, gx = x0 + c - 1;
        patch[ci][r][c] = (gy >= 0 && gy < HH && gx >= 0 && gx < WW)
                              ? in[(size_t)ci * HW + gy * WW + gx] : 0.f;
    }
    __syncthreads();
    const int g = tid & 7;
    const int p = tid >> 3;
    const int py = p >> 4, px = p & 15;
    float acc[8];
#pragma unroll
    for (int j = 0; j < 8; ++j) acc[j] = bias[g * 8 + j];
#pragma unroll
    for (int ci = 0; ci < 3; ++ci)
#pragma unroll
        for (int k = 0; k < 9; ++k) {
            const int ky = k / 3, kx = k - 3 * ky;
            const float v = patch[ci][py + ky][px + kx];
#pragma unroll
            for (int j = 0; j < 8; ++j)
                acc[j] = fmaf(v, wl[(g * 8 + j) * 27 + ci * 9 + k], acc[j]);
        }
    unsigned short ov[8];
#pragma unroll
    for (int j = 0; j < 8; ++j) ov[j] = f2bf(fmaxf(acc[j], 0.f));
    const int y = y0 + py, x = x0 + px;
    *(float4*)(out + ((size_t)y * WW + x) * 64 + g * 8) = *(const float4*)ov;
}

// ---------------------------------------------------------------------------
// Bilinear warp, border padding, align_corners=True. NHWC bf16 32ch.
// ---------------------------------------------------------------------------
__global__ __launch_bounds__(256) void warp_k(
    const unsigned short* __restrict__ f2, const float* __restrict__ flow,
    unsigned short* __restrict__ outp)
{
    int idx = blockIdx.x * 256 + threadIdx.x;
    if (idx >= HW) return;
    int y = idx / WW, x = idx - y * WW;
    float px_ = (float)x + flow[idx];
    float py_ = (float)y + flow[idx + HW];
    px_ = fminf(fmaxf(px_, 0.f), (float)(WW - 1));
    py_ = fminf(fmaxf(py_, 0.f), (float)(HH - 1));
    float fx0 = floorf(px_), fy0 = floorf(py_);
    int xi0 = (int)fx0, yi0 = (int)fy0;
    int xi1 = min(xi0 + 1, WW - 1), yi1 = min(yi0 + 1, HH - 1);
    float wx = px_ - fx0, wy = py_ - fy0;
    float w00 = (1.f - wx) * (1.f - wy), w01 = wx * (1.f - wy);
    float w10 = (1.f - wx) * wy, w11 = wx * wy;

    const uint32* a = (const uint32*)(f2 + ((size_t)yi0 * WW + xi0) * 32);
    const uint32* b = (const uint32*)(f2 + ((size_t)yi0 * WW + xi1) * 32);
    const uint32* c = (const uint32*)(f2 + ((size_t)yi1 * WW + xi0) * 32);
    const uint32* d = (const uint32*)(f2 + ((size_t)yi1 * WW + xi1) * 32);
    uint32 ov[16];
#pragma unroll
    for (int i = 0; i < 16; ++i) {
        uint32 wa = a[i], wb = b[i], wc = c[i], wd = d[i];
        float lo = __uint_as_float(wa << 16) * w00 + __uint_as_float(wb << 16) * w01 +
                   __uint_as_float(wc << 16) * w10 + __uint_as_float(wd << 16) * w11;
        float hi = __uint_as_float(wa & 0xffff0000u) * w00 + __uint_as_float(wb & 0xffff0000u) * w01 +
                   __uint_as_float(wc & 0xffff0000u) * w10 + __uint_as_float(wd & 0xffff0000u) * w11;
        ov[i] = ((uint32)f2bf(hi) << 16) | f2bf(lo);
    }
    uint32* o = (uint32*)(outp + (size_t)idx * 32);
#pragma unroll
    for (int i = 0; i < 16; ++i) o[i] = ov[i];
}

// ---------------------------------------------------------------------------
// Cost volume tile kernel. Block = 128 threads = 16x8 px tile, one thread
// per pixel. f2w halo (16 rows x 24 cols x 32ch, stride 36 shorts ->
// conflict-free-ish b64 reads) staged in LDS; f1 pixel vector in registers.
// Integer offsets through bilinear_border == border-clamped integer shifts.
// Writes the full 96-ch NHWC row per pixel (81 cost + 2 flow + 13 zero);
// all writes to a line come from one block -> L2 merges -> no write amp.
// ---------------------------------------------------------------------------
__global__ __launch_bounds__(128) void cost_tile_k(
    const unsigned short* __restrict__ f1, const unsigned short* __restrict__ f2w,
    const float* __restrict__ flow, unsigned short* __restrict__ hb)
{
    __shared__ unsigned short ldsG[16 * 24 * 36];  // 27648 B
    const int tid = threadIdx.x;
    const int x0 = blockIdx.x * 16;
    const int y0 = blockIdx.y * 8;

    // Stage halo: 384 px * 32ch as uint2 (4 ch) pieces: 3072 loads / 128 thr.
#pragma unroll
    for (int i = 0; i < 24; ++i) {
        int idx = i * 128 + tid;   // 0..3071
        int hp = idx >> 3;         // halo pixel 0..383
        int c4 = idx & 7;          // 4-channel group
        int ry = hp / 24, rx = hp - ry * 24;
        int gy = min(max(y0 + ry - 4, 0), HH - 1);
        int gx = min(max(x0 + rx - 4, 0), WW - 1);
        *(uint2*)(ldsG + hp * 36 + c4 * 4) =
            *(const uint2*)(f2w + ((size_t)gy * WW + gx) * 32 + c4 * 4);
    }
    __syncthreads();

    const int tyy = tid >> 4, txx = tid & 15;
    const int px = (y0 + tyy) * WW + (x0 + txx);

    // f1 pixel vector -> 32 fp32 regs.
    float f[32];
    const uint2* fp = (const uint2*)(f1 + (size_t)px * 32);
#pragma unroll
    for (int j = 0; j < 8; ++j) {
        uint2 w = fp[j];
        f[4 * j + 0] = __uint_as_float(w.x << 16);
        f[4 * j + 1] = __uint_as_float(w.x & 0xffff0000u);
        f[4 * j + 2] = __uint_as_float(w.y << 16);
        f[4 * j + 3] = __uint_as_float(w.y & 0xffff0000u);
    }

    unsigned short* hq = hb + (size_t)px * 96;
    for (int dyi = 0; dyi < 9; ++dyi) {  // not unrolled (I$)
        const unsigned short* gp0 = ldsG + ((tyy + dyi) * 24 + txx) * 36;
#pragma unroll
        for (int dxi = 0; dxi < 9; ++dxi) {
            const unsigned short* gp = gp0 + dxi * 36;
            float s = 0.f;
#pragma unroll
            for (int j = 0; j < 8; ++j) {
                uint2 g = *(const uint2*)(gp + j * 4);
                s = fmaf(f[4 * j + 0], __uint_as_float(g.x << 16), s);
                s = fmaf(f[4 * j + 1], __uint_as_float(g.x & 0xffff0000u), s);
                s = fmaf(f[4 * j + 2], __uint_as_float(g.y << 16), s);
                s = fmaf(f[4 * j + 3], __uint_as_float(g.y & 0xffff0000u), s);
            }
            hq[dyi * 9 + dxi] = f2bf(s);
        }
    }
    hq[81] = f2bf(flow[px]);
    hq[82] = f2bf(flow[px + HW]);
#pragma unroll
    for (int c = 83; c < 96; ++c) hq[c] = 0;
}

// ---------------------------------------------------------------------------
// rconv4: 64 -> 2, + initial_flow residual, fp32 NCHW output, no ReLU.
// ---------------------------------------------------------------------------
__global__ __launch_bounds__(256) void rconv4_k(
    const unsigned short* __restrict__ in, const float* __restrict__ w,
    const float* __restrict__ bias, const float* __restrict__ flow,
    float* __restrict__ out)
{
    __shared__ float wl[1152];  // 2*64*9
    for (int i = threadIdx.x; i < 1152; i += 256) wl[i] = w[i];
    __syncthreads();
    int px = blockIdx.x * 256 + threadIdx.x;
    if (px >= HW) return;
    int y = px / WW, x = px - y * WW;
    float a0 = bias[0], a1 = bias[1];
    for (int ky = 0; ky < 3; ++ky) {
        int gy = y + ky - 1;
        if (gy < 0 || gy >= HH) continue;
        for (int kx = 0; kx < 3; ++kx) {
            int gx = x + kx - 1;
            if (gx < 0 || gx >= WW) continue;
            const uint32* p = (const uint32*)(in + ((size_t)gy * WW + gx) * 64);
            int tap = ky * 3 + kx;
#pragma unroll
            for (int i = 0; i < 32; ++i) {
                uint32 wv = p[i];
                float lo = __uint_as_float(wv << 16);
                float hi = __uint_as_float(wv & 0xffff0000u);
                a0 = fmaf(lo, wl[(2 * i) * 9 + tap], a0);
                a0 = fmaf(hi, wl[(2 * i + 1) * 9 + tap], a0);
                a1 = fmaf(lo, wl[576 + (2 * i) * 9 + tap], a1);
                a1 = fmaf(hi, wl[576 + (2 * i + 1) * 9 + tap], a1);
            }
        }
    }
    out[px] = flow[px] + a0;
    out[px + HW] = flow[px + HW] + a1;
}

extern "C" void kernel_launch(void* const* d_in, const int* in_sizes, int n_in,
                              void* d_out, int out_size, void* d_ws, size_t ws_size,
                              hipStream_t stream)
{
    (void)in_sizes; (void)n_in; (void)out_size; (void)ws_size;
    const float* feat1 = (const float*)d_in[0];
    const float* feat2 = (const float*)d_in[1];
    const float* iflow = (const float*)d_in[2];
    const float* fW1 = (const float*)d_in[3];  const float* fb1 = (const float*)d_in[4];
    const float* fW2 = (const float*)d_in[5];  const float* fb2 = (const float*)d_in[6];
    const float* fW3 = (const float*)d_in[7];  const float* fb3 = (const float*)d_in[8];
    const float* rW1 = (const float*)d_in[9];  const float* rb1 = (const float*)d_in[10];
    const float* rW2 = (const float*)d_in[11]; const float* rb2 = (const float*)d_in[12];
    const float* rW3 = (const float*)d_in[13]; const float* rb3 = (const float*)d_in[14];
    const float* rW4 = (const float*)d_in[15]; const float* rb4 = (const float*)d_in[16];
    float* out = (float*)d_out;

    // Arena (bf16 elems). Per-batch buffers, reused across the 2 batches.
    // [X0 64][X1 64][F1 32][F2 32][F2W 32][Hb 96] = 320*HW elems (~73.4 MB)
    // R1 <- X0..X1 (128), R2 <- F2W..Hb (32+96=128), R3 <- F1..F2 (64).
    unsigned short* ws0 = (unsigned short*)d_ws;
    const size_t P = (size_t)HW;
    unsigned short* X0  = ws0;
    unsigned short* X1  = X0 + 64 * P;
    unsigned short* F1  = X1 + 64 * P;
    unsigned short* F2  = F1 + 32 * P;
    unsigned short* F2W = F2 + 32 * P;
    unsigned short* Hb  = F2W + 32 * P;
    unsigned short* R1  = X0;
    unsigned short* R2  = F2W;
    unsigned short* R3  = F1;
    unsigned short* wp2  = Hb + 96 * P;            // fconv2: 9*64*64
    unsigned short* wp3  = wp2 + 9 * 64 * 64;      // fconv3: 9*64*32
    unsigned short* wpr1 = wp3 + 9 * 64 * 32;      // rconv1: 9*96*128
    unsigned short* wpr2 = wpr1 + 9 * 96 * 128;    // rconv2: 9*128*128
    unsigned short* wpr3 = wpr2 + 9 * 128 * 128;   // rconv3: 9*128*64

    const dim3 blk(256);
    // Pack all conv weights (cheap, idempotent).
    pack_w_k<<<dim3((9 * 64 * 64 + 255) / 256), blk, 0, stream>>>(fW2, wp2, 64, 64, 64);
    pack_w_k<<<dim3((9 * 64 * 32 + 255) / 256), blk, 0, stream>>>(fW3, wp3, 64, 64, 32);
    pack_w_k<<<dim3((9 * 96 * 128 + 255) / 256), blk, 0, stream>>>(rW1, wpr1, 83, 96, 128);
    pack_w_k<<<dim3((9 * 128 * 128 + 255) / 256), blk, 0, stream>>>(rW2, wpr2, 128, 128, 128);
    pack_w_k<<<dim3((9 * 128 * 64 + 255) / 256), blk, 0, stream>>>(rW3, wpr3, 128, 128, 64);

    const dim3 gConv(WW / 16, HH / 8);   // 28 x 32
    const dim3 gF1(WW / 16, HH / 2);     // 28 x 128
    const int gPix = (HW + 255) / 256;

    for (int b = 0; b < 2; ++b) {
        const float* f1in = feat1 + (size_t)b * 3 * HW;
        const float* f2in = feat2 + (size_t)b * 3 * HW;
        const float* flw  = iflow + (size_t)b * 2 * HW;
        float* outb = out + (size_t)b * 2 * HW;

        // feat2 branch -> warped features
        fconv1_k<<<gF1, blk, 0, stream>>>(f2in, fW1, fb1, X0);
        convmfma_k<64, 64, 1><<<gConv, blk, 0, stream>>>(X0, wp2, fb2, X1);
        convmfma_k<64, 32, 1><<<gConv, blk, 0, stream>>>(X1, wp3, fb3, F2);
        warp_k<<<dim3(gPix), blk, 0, stream>>>(F2, flw, F2W);

        // feat1 branch
        fconv1_k<<<gF1, blk, 0, stream>>>(f1in, fW1, fb1, X0);
        convmfma_k<64, 64, 1><<<gConv, blk, 0, stream>>>(X0, wp2, fb2, X1);
        convmfma_k<64, 32, 1><<<gConv, blk, 0, stream>>>(X1, wp3, fb3, F1);

        // Cost volume (+ flow channels + zero pad) -> Hb (96ch NHWC)
        cost_tile_k<<<dim3(WW / 16, HH / 8), dim3(128), 0, stream>>>(F1, F2W, flw, Hb);

        // Refinement head
        convmfma_k<96, 128, 1><<<gConv, blk, 0, stream>>>(Hb, wpr1, rb1, R1);
        convmfma_k<128, 128, 1><<<gConv, blk, 0, stream>>>(R1, wpr2, rb2, R2);
        convmfma_k<128, 64, 1><<<gConv, blk, 0, stream>>>(R2, wpr3, rb3, R3);
        rconv4_k<<<dim3(gPix), blk, 0, stream>>>(R3, rW4, rb4, flw, outb);
    }
}

// Round 5
// 598.517 us; speedup vs baseline: 10.1459x; 1.0969x over previous
//
#include <hip/hip_runtime.h>

// B=2, H=256, W=448. bf16 MFMA for the 5 big convs.
// Round 5: batch-merged dispatches (grid.z = nb) gated on ws_size, fused pack.
#define HH 256
#define WW 448
#define HW (HH * WW)

typedef short bf16x8 __attribute__((ext_vector_type(8)));
typedef float f32x4 __attribute__((ext_vector_type(4)));
typedef unsigned int uint32;
typedef unsigned short ushort;

__device__ __forceinline__ ushort f2bf(float f) {
    uint32 u = __float_as_uint(f);
    u += 0x7fffu + ((u >> 16) & 1u);  // RNE
    return (ushort)(u >> 16);
}

// ---------------------------------------------------------------------------
// Weight repack (all 5 convs in one kernel): fp32 OIHW -> bf16 [tap][kc][n][32]
// ---------------------------------------------------------------------------
__device__ __forceinline__ void pack_one(
    int i, const float* __restrict__ w, ushort* __restrict__ wp,
    int CinReal, int CinPad, int Cout)
{
    int total = 9 * CinPad * Cout;
    if (i >= total) return;
    int ci = i & 31;
    int rest = i >> 5;
    int n = rest % Cout;
    int rest2 = rest / Cout;
    int KC = CinPad / 32;
    int kc = rest2 % KC;
    int tap = rest2 / KC;
    int cin = kc * 32 + ci;
    float v = (cin < CinReal) ? w[((size_t)n * CinReal + cin) * 9 + tap] : 0.f;
    wp[i] = f2bf(v);
}

__global__ __launch_bounds__(256) void pack_all_k(
    const float* fW2, const float* fW3, const float* rW1,
    const float* rW2, const float* rW3,
    ushort* wp2, ushort* wp3, ushort* wpr1, ushort* wpr2, ushort* wpr3)
{
    int i = blockIdx.x * 256 + threadIdx.x;
    pack_one(i, fW2, wp2, 64, 64, 64);
    pack_one(i, fW3, wp3, 64, 64, 32);
    pack_one(i, rW1, wpr1, 83, 96, 128);
    pack_one(i, rW2, wpr2, 128, 128, 128);
    pack_one(i, rW3, wpr3, 128, 128, 64);
}

// ---------------------------------------------------------------------------
// MFMA implicit-GEMM 3x3 SAME conv. NHWC bf16 in/out, fp32 bias, optional
// ReLU. Block 256 = 4 waves; tile = 8 rows x 16 cols = 128 px; full Cin halo
// patch (10x18xCin, stride Cin+8) staged once. grid.z = batch.
// mfma_f32_16x16x32_bf16: A[m=lane&15][k=quad*8+j], B[k=quad*8+j][n=lane&15],
// D row m=quad*4+reg, col n=lane&15.
// ---------------------------------------------------------------------------
template <int CIN, int COUT, int RELU>
__global__ __launch_bounds__(256) void convmfma_k(
    const ushort* __restrict__ in, const ushort* __restrict__ wp,
    const float* __restrict__ bias, ushort* __restrict__ out,
    long inStride, long outStride)
{
    constexpr int KC = CIN / 32;
    constexpr int CS = CIN + 8;
    constexpr int MG = (COUT == 32) ? 4 : 2;
    constexpr int WM = 8 / MG;
    constexpr int NG = 4 / MG;
    constexpr int WN = (COUT / 16) / NG;
    constexpr int CH8 = CIN / 8;

    __shared__ __align__(16) ushort lds[180 * CS];

    const int tid = threadIdx.x;
    const int x0 = blockIdx.x * 16;
    const int y0 = blockIdx.y * 8;
    in += (size_t)blockIdx.z * inStride;
    out += (size_t)blockIdx.z * outStride;

    for (int i = tid; i < 180 * CH8; i += 256) {
        int p = i / CH8, c8 = i - p * CH8;
        int ry = p / 18, rx = p - ry * 18;
        int gy = y0 + ry - 1, gx = x0 + rx - 1;
        float4 v = make_float4(0.f, 0.f, 0.f, 0.f);
        if (gy >= 0 && gy < HH && gx >= 0 && gx < WW)
            v = *(const float4*)(in + ((size_t)gy * WW + gx) * CIN + c8 * 8);
        *(float4*)(lds + p * CS + c8 * 8) = v;
    }
    __syncthreads();

    const int wv = tid >> 6;
    const int lane = tid & 63;
    const int m = lane & 15;
    const int quad = lane >> 4;
    const int mbase = (wv % MG) * WM;
    const int nbase = (wv / MG) * WN * 16;

    f32x4 acc[WM][WN];
#pragma unroll
    for (int t = 0; t < WM; ++t)
#pragma unroll
        for (int u = 0; u < WN; ++u)
            acc[t][u] = (f32x4){0.f, 0.f, 0.f, 0.f};

    for (int tap = 0; tap < 9; ++tap) {
        const int ky = tap / 3;
        const int kx = tap - 3 * ky;
#pragma unroll
        for (int kc = 0; kc < KC; ++kc) {
            bf16x8 a[WM], b[WN];
#pragma unroll
            for (int t = 0; t < WM; ++t)
                a[t] = *(const bf16x8*)(lds +
                        ((mbase + t + ky) * 18 + (m + kx)) * CS + kc * 32 + quad * 8);
#pragma unroll
            for (int u = 0; u < WN; ++u)
                b[u] = *(const bf16x8*)(wp +
                        ((size_t)(tap * KC + kc) * COUT + nbase + u * 16 + m) * 32 + quad * 8);
#pragma unroll
            for (int t = 0; t < WM; ++t)
#pragma unroll
                for (int u = 0; u < WN; ++u)
                    acc[t][u] = __builtin_amdgcn_mfma_f32_16x16x32_bf16(
                        a[t], b[u], acc[t][u], 0, 0, 0);
        }
    }

#pragma unroll
    for (int u = 0; u < WN; ++u) {
        const int n = nbase + u * 16 + m;
        const float bs = bias[n];
#pragma unroll
        for (int t = 0; t < WM; ++t) {
            const int y = y0 + mbase + t;
#pragma unroll
            for (int r = 0; r < 4; ++r) {
                const int x = x0 + quad * 4 + r;
                float v = acc[t][u][r] + bs;
                if (RELU) v = fmaxf(v, 0.f);
                out[((size_t)y * WW + x) * COUT + n] = f2bf(v);
            }
        }
    }
}

// ---------------------------------------------------------------------------
// fconv1: fp32 NCHW (3,H,W) -> bf16 NHWC 64ch, ReLU. grid.z = batch.
// ---------------------------------------------------------------------------
__global__ __launch_bounds__(256) void fconv1_k(
    const float* __restrict__ in, const float* __restrict__ w,
    const float* __restrict__ bias, ushort* __restrict__ out,
    long inStride, long outStride)
{
    __shared__ float wl[1728];
    __shared__ float patch[3][4][18];
    const int tid = threadIdx.x;
    const int x0 = blockIdx.x * 16, y0 = blockIdx.y * 2;
    in += (size_t)blockIdx.z * inStride;
    out += (size_t)blockIdx.z * outStride;
    for (int i = tid; i < 1728; i += 256) wl[i] = w[i];
    for (int i = tid; i < 216; i += 256) {
        int ci = i / 72;
        int r = (i - ci * 72) / 18;
        int c = i - ci * 72 - r * 18;
        int gy = y0 + r - 1, gx = x0 + c - 1;
        patch[ci][r][c] = (gy >= 0 && gy < HH && gx >= 0 && gx < WW)
                              ? in[(size_t)ci * HW + gy * WW + gx] : 0.f;
    }
    __syncthreads();
    const int g = tid & 7;
    const int p = tid >> 3;
    const int py = p >> 4, px = p & 15;
    float acc[8];
#pragma unroll
    for (int j = 0; j < 8; ++j) acc[j] = bias[g * 8 + j];
#pragma unroll
    for (int ci = 0; ci < 3; ++ci)
#pragma unroll
        for (int k = 0; k < 9; ++k) {
            const int ky = k / 3, kx = k - 3 * ky;
            const float v = patch[ci][py + ky][px + kx];
#pragma unroll
            for (int j = 0; j < 8; ++j)
                acc[j] = fmaf(v, wl[(g * 8 + j) * 27 + ci * 9 + k], acc[j]);
        }
    ushort ov[8];
#pragma unroll
    for (int j = 0; j < 8; ++j) ov[j] = f2bf(fmaxf(acc[j], 0.f));
    const int y = y0 + py, x = x0 + px;
    *(float4*)(out + ((size_t)y * WW + x) * 64 + g * 8) = *(const float4*)ov;
}

// ---------------------------------------------------------------------------
// Bilinear warp, border padding, align_corners=True. NHWC bf16 32ch.
// grid.y = batch.
// ---------------------------------------------------------------------------
__global__ __launch_bounds__(256) void warp_k(
    const ushort* __restrict__ f2, const float* __restrict__ flow,
    ushort* __restrict__ outp, long fStride, long flowStride, long oStride)
{
    int idx = blockIdx.x * 256 + threadIdx.x;
    if (idx >= HW) return;
    f2 += (size_t)blockIdx.y * fStride;
    flow += (size_t)blockIdx.y * flowStride;
    outp += (size_t)blockIdx.y * oStride;
    int y = idx / WW, x = idx - y * WW;
    float px_ = (float)x + flow[idx];
    float py_ = (float)y + flow[idx + HW];
    px_ = fminf(fmaxf(px_, 0.f), (float)(WW - 1));
    py_ = fminf(fmaxf(py_, 0.f), (float)(HH - 1));
    float fx0 = floorf(px_), fy0 = floorf(py_);
    int xi0 = (int)fx0, yi0 = (int)fy0;
    int xi1 = min(xi0 + 1, WW - 1), yi1 = min(yi0 + 1, HH - 1);
    float wx = px_ - fx0, wy = py_ - fy0;
    float w00 = (1.f - wx) * (1.f - wy), w01 = wx * (1.f - wy);
    float w10 = (1.f - wx) * wy, w11 = wx * wy;

    const uint32* a = (const uint32*)(f2 + ((size_t)yi0 * WW + xi0) * 32);
    const uint32* b = (const uint32*)(f2 + ((size_t)yi0 * WW + xi1) * 32);
    const uint32* c = (const uint32*)(f2 + ((size_t)yi1 * WW + xi0) * 32);
    const uint32* d = (const uint32*)(f2 + ((size_t)yi1 * WW + xi1) * 32);
    uint32 ov[16];
#pragma unroll
    for (int i = 0; i < 16; ++i) {
        uint32 wa = a[i], wb = b[i], wc = c[i], wd = d[i];
        float lo = __uint_as_float(wa << 16) * w00 + __uint_as_float(wb << 16) * w01 +
                   __uint_as_float(wc << 16) * w10 + __uint_as_float(wd << 16) * w11;
        float hi = __uint_as_float(wa & 0xffff0000u) * w00 + __uint_as_float(wb & 0xffff0000u) * w01 +
                   __uint_as_float(wc & 0xffff0000u) * w10 + __uint_as_float(wd & 0xffff0000u) * w11;
        ov[i] = ((uint32)f2bf(hi) << 16) | f2bf(lo);
    }
    uint32* o = (uint32*)(outp + (size_t)idx * 32);
#pragma unroll
    for (int i = 0; i < 16; ++i) o[i] = ov[i];
}

// ---------------------------------------------------------------------------
// Cost volume tile kernel. Block = 128 threads = 16x8 px tile. grid.z = batch.
// ---------------------------------------------------------------------------
__global__ __launch_bounds__(128) void cost_tile_k(
    const ushort* __restrict__ f1, const ushort* __restrict__ f2w,
    const float* __restrict__ flow, ushort* __restrict__ hb,
    long aStride, long flowStride)
{
    __shared__ ushort ldsG[16 * 24 * 36];
    const int tid = threadIdx.x;
    const int x0 = blockIdx.x * 16;
    const int y0 = blockIdx.y * 8;
    f1 += (size_t)blockIdx.z * aStride;
    f2w += (size_t)blockIdx.z * aStride;
    hb += (size_t)blockIdx.z * aStride;
    flow += (size_t)blockIdx.z * flowStride;

#pragma unroll
    for (int i = 0; i < 24; ++i) {
        int idx = i * 128 + tid;
        int hp = idx >> 3;
        int c4 = idx & 7;
        int ry = hp / 24, rx = hp - ry * 24;
        int gy = min(max(y0 + ry - 4, 0), HH - 1);
        int gx = min(max(x0 + rx - 4, 0), WW - 1);
        *(uint2*)(ldsG + hp * 36 + c4 * 4) =
            *(const uint2*)(f2w + ((size_t)gy * WW + gx) * 32 + c4 * 4);
    }
    __syncthreads();

    const int tyy = tid >> 4, txx = tid & 15;
    const int px = (y0 + tyy) * WW + (x0 + txx);

    float f[32];
    const uint2* fp = (const uint2*)(f1 + (size_t)px * 32);
#pragma unroll
    for (int j = 0; j < 8; ++j) {
        uint2 w = fp[j];
        f[4 * j + 0] = __uint_as_float(w.x << 16);
        f[4 * j + 1] = __uint_as_float(w.x & 0xffff0000u);
        f[4 * j + 2] = __uint_as_float(w.y << 16);
        f[4 * j + 3] = __uint_as_float(w.y & 0xffff0000u);
    }

    ushort* hq = hb + (size_t)px * 96;
    for (int dyi = 0; dyi < 9; ++dyi) {
        const ushort* gp0 = ldsG + ((tyy + dyi) * 24 + txx) * 36;
#pragma unroll
        for (int dxi = 0; dxi < 9; ++dxi) {
            const ushort* gp = gp0 + dxi * 36;
            float s = 0.f;
#pragma unroll
            for (int j = 0; j < 8; ++j) {
                uint2 g = *(const uint2*)(gp + j * 4);
                s = fmaf(f[4 * j + 0], __uint_as_float(g.x << 16), s);
                s = fmaf(f[4 * j + 1], __uint_as_float(g.x & 0xffff0000u), s);
                s = fmaf(f[4 * j + 2], __uint_as_float(g.y << 16), s);
                s = fmaf(f[4 * j + 3], __uint_as_float(g.y & 0xffff0000u), s);
            }
            hq[dyi * 9 + dxi] = f2bf(s);
        }
    }
    hq[81] = f2bf(flow[px]);
    hq[82] = f2bf(flow[px + HW]);
#pragma unroll
    for (int c = 83; c < 96; ++c) hq[c] = 0;
}

// ---------------------------------------------------------------------------
// rconv4: 64 -> 2, + initial_flow residual, fp32 NCHW output. grid.y = batch.
// ---------------------------------------------------------------------------
__global__ __launch_bounds__(256) void rconv4_k(
    const ushort* __restrict__ in, const float* __restrict__ w,
    const float* __restrict__ bias, const float* __restrict__ flow,
    float* __restrict__ out, long inStride, long ioStride)
{
    __shared__ float wl[1152];
    for (int i = threadIdx.x; i < 1152; i += 256) wl[i] = w[i];
    __syncthreads();
    in += (size_t)blockIdx.y * inStride;
    flow += (size_t)blockIdx.y * ioStride;
    out += (size_t)blockIdx.y * ioStride;
    int px = blockIdx.x * 256 + threadIdx.x;
    if (px >= HW) return;
    int y = px / WW, x = px - y * WW;
    float a0 = bias[0], a1 = bias[1];
    for (int ky = 0; ky < 3; ++ky) {
        int gy = y + ky - 1;
        if (gy < 0 || gy >= HH) continue;
        for (int kx = 0; kx < 3; ++kx) {
            int gx = x + kx - 1;
            if (gx < 0 || gx >= WW) continue;
            const uint32* p = (const uint32*)(in + ((size_t)gy * WW + gx) * 64);
            int tap = ky * 3 + kx;
#pragma unroll
            for (int i = 0; i < 32; ++i) {
                uint32 wv = p[i];
                float lo = __uint_as_float(wv << 16);
                float hi = __uint_as_float(wv & 0xffff0000u);
                a0 = fmaf(lo, wl[(2 * i) * 9 + tap], a0);
                a0 = fmaf(hi, wl[(2 * i + 1) * 9 + tap], a0);
                a1 = fmaf(lo, wl[576 + (2 * i) * 9 + tap], a1);
                a1 = fmaf(hi, wl[576 + (2 * i + 1) * 9 + tap], a1);
            }
        }
    }
    out[px] = flow[px] + a0;
    out[px + HW] = flow[px + HW] + a1;
}

extern "C" void kernel_launch(void* const* d_in, const int* in_sizes, int n_in,
                              void* d_out, int out_size, void* d_ws, size_t ws_size,
                              hipStream_t stream)
{
    (void)in_sizes; (void)n_in; (void)out_size;
    const float* feat1 = (const float*)d_in[0];
    const float* feat2 = (const float*)d_in[1];
    const float* iflow = (const float*)d_in[2];
    const float* fW1 = (const float*)d_in[3];  const float* fb1 = (const float*)d_in[4];
    const float* fW2 = (const float*)d_in[5];  const float* fb2 = (const float*)d_in[6];
    const float* fW3 = (const float*)d_in[7];  const float* fb3 = (const float*)d_in[8];
    const float* rW1 = (const float*)d_in[9];  const float* rb1 = (const float*)d_in[10];
    const float* rW2 = (const float*)d_in[11]; const float* rb2 = (const float*)d_in[12];
    const float* rW3 = (const float*)d_in[13]; const float* rb3 = (const float*)d_in[14];
    const float* rW4 = (const float*)d_in[15]; const float* rb4 = (const float*)d_in[16];
    float* out = (float*)d_out;

    // Workspace layout (bf16 elems): [packed weights][arena b0][arena b1?]
    // Arena (per batch, 320 planes): X0 64 | X1 64 | F1 32 | F2 32 | F2W 32 | Hb 96
    // Aliases: R1 <- X0..X1 (128), R2 <- F2W..Hb (128), R3 <- F1..F2 (64).
    const size_t P = (size_t)HW;
    const size_t WTOT = (size_t)9 * (64 * 64 + 64 * 32 + 96 * 128 + 128 * 128 + 128 * 64);
    const size_t ARENA = 320 * P;
    ushort* ws0 = (ushort*)d_ws;
    ushort* wp2  = ws0;
    ushort* wp3  = wp2 + 9 * 64 * 64;
    ushort* wpr1 = wp3 + 9 * 64 * 32;
    ushort* wpr2 = wpr1 + 9 * 96 * 128;
    ushort* wpr3 = wpr2 + 9 * 128 * 128;
    ushort* arena = ws0 + WTOT;

    const bool merged = ws_size >= (WTOT + 2 * ARENA) * sizeof(ushort);
    const int nb = merged ? 2 : 1;
    const int nloop = merged ? 1 : 2;
    const long aS = merged ? (long)ARENA : 0;   // arena batch stride
    const long s3 = merged ? (long)(3 * P) : 0; // input batch strides
    const long s2 = merged ? (long)(2 * P) : 0;

    ushort* X0  = arena;
    ushort* X1  = X0 + 64 * P;
    ushort* F1  = X1 + 64 * P;
    ushort* F2  = F1 + 32 * P;
    ushort* F2W = F2 + 32 * P;
    ushort* Hb  = F2W + 32 * P;
    ushort* R1  = X0;
    ushort* R2  = F2W;
    ushort* R3  = F1;

    const dim3 blk(256);
    pack_all_k<<<dim3((9 * 128 * 128 + 255) / 256), blk, 0, stream>>>(
        fW2, fW3, rW1, rW2, rW3, wp2, wp3, wpr1, wpr2, wpr3);

    const dim3 gConv(WW / 16, HH / 8, nb);   // 28 x 32 x nb
    const dim3 gF1(WW / 16, HH / 2, nb);     // 28 x 128 x nb
    const dim3 gCost(WW / 16, HH / 8, nb);
    const int gPix = (HW + 255) / 256;

    for (int lb = 0; lb < nloop; ++lb) {
        const float* f1in = feat1 + (size_t)lb * 3 * P;
        const float* f2in = feat2 + (size_t)lb * 3 * P;
        const float* flw  = iflow + (size_t)lb * 2 * P;
        float* outb = out + (size_t)lb * 2 * P;

        // feat2 branch -> warped features
        fconv1_k<<<gF1, blk, 0, stream>>>(f2in, fW1, fb1, X0, s3, aS);
        convmfma_k<64, 64, 1><<<gConv, blk, 0, stream>>>(X0, wp2, fb2, X1, aS, aS);
        convmfma_k<64, 32, 1><<<gConv, blk, 0, stream>>>(X1, wp3, fb3, F2, aS, aS);
        warp_k<<<dim3(gPix, nb), blk, 0, stream>>>(F2, flw, F2W, aS, s2, aS);

        // feat1 branch
        fconv1_k<<<gF1, blk, 0, stream>>>(f1in, fW1, fb1, X0, s3, aS);
        convmfma_k<64, 64, 1><<<gConv, blk, 0, stream>>>(X0, wp2, fb2, X1, aS, aS);
        convmfma_k<64, 32, 1><<<gConv, blk, 0, stream>>>(X1, wp3, fb3, F1, aS, aS);

        // Cost volume (+ flow + zero pad) -> Hb (96ch NHWC)
        cost_tile_k<<<gCost, dim3(128), 0, stream>>>(F1, F2W, flw, Hb, aS, s2);

        // Refinement head
        convmfma_k<96, 128, 1><<<gConv, blk, 0, stream>>>(Hb, wpr1, rb1, R1, aS, aS);
        convmfma_k<128, 128, 1><<<gConv, blk, 0, stream>>>(R1, wpr2, rb2, R2, aS, aS);
        convmfma_k<128, 64, 1><<<gConv, blk, 0, stream>>>(R2, wpr3, rb3, R3, aS, aS);
        rconv4_k<<<dim3(gPix, nb), blk, 0, stream>>>(R3, rW4, rb4, flw, outb, aS, s2);
    }
}